// Round 1
// baseline (350.769 us; speedup 1.0000x reference)
//
#include <hip/hip_runtime.h>
#include <cstdint>

typedef unsigned short u16;
typedef __bf16 bf16_t;
typedef bf16_t bf16x8 __attribute__((ext_vector_type(8)));
typedef float f32x4 __attribute__((ext_vector_type(4)));
typedef u16 u16x8 __attribute__((ext_vector_type(8)));
typedef u16 u16x4 __attribute__((ext_vector_type(4)));

#define DEV __device__ __forceinline__

DEV u16 f2b(float f) {
    uint32_t u = __builtin_bit_cast(uint32_t, f);
    u += 0x7FFFu + ((u >> 16) & 1u);
    return (u16)(u >> 16);
}
DEV float b2f(u16 h) { return __builtin_bit_cast(float, (uint32_t)h << 16); }

DEV bf16x8 load8(const u16* p) {
    return __builtin_bit_cast(bf16x8, *reinterpret_cast<const u16x8*>(p));
}

DEV void async16(void* lds, const void* g) {
    __builtin_amdgcn_global_load_lds(
        reinterpret_cast<const __attribute__((address_space(1))) void*>(
            reinterpret_cast<uintptr_t>(g)),
        reinterpret_cast<__attribute__((address_space(3))) void*>(
            reinterpret_cast<uintptr_t>(lds)),
        16, 0, 0);
}

DEV float gelu_t(float x) {
    float z = 0.7978845608028654f * (x + 0.044715f * x * x * x);
    z = fminf(fmaxf(z, -15.0f), 15.0f);
    float e = __expf(2.0f * z);
    return 0.5f * x * (1.0f + (e - 1.0f) / (e + 1.0f));
}

// ---------------- LayerNorm: 1 wave per row of 768 fp32 -> bf16 ----------------
__global__ __launch_bounds__(256) void ln_k(const float* __restrict__ x,
                                            const float* __restrict__ g,
                                            const float* __restrict__ bb,
                                            u16* __restrict__ out) {
    const int lane = threadIdx.x & 63, w = threadIdx.x >> 6;
    const int row = blockIdx.x * 4 + w;
    const float4* xr = reinterpret_cast<const float4*>(x + (size_t)row * 768);
    float4 v[3];
    float s = 0.f, s2 = 0.f;
#pragma unroll
    for (int i = 0; i < 3; ++i) {
        v[i] = xr[i * 64 + lane];
        s += v[i].x + v[i].y + v[i].z + v[i].w;
        s2 += v[i].x * v[i].x + v[i].y * v[i].y + v[i].z * v[i].z + v[i].w * v[i].w;
    }
#pragma unroll
    for (int off = 1; off < 64; off <<= 1) {
        s += __shfl_xor(s, off);
        s2 += __shfl_xor(s2, off);
    }
    const float mu = s * (1.0f / 768.0f);
    const float rstd = rsqrtf(s2 * (1.0f / 768.0f) - mu * mu + 1e-5f);
#pragma unroll
    for (int i = 0; i < 3; ++i) {
        int col = i * 256 + lane * 4;
        u16x4 o;
        o[0] = f2b((v[i].x - mu) * rstd * g[col + 0] + bb[col + 0]);
        o[1] = f2b((v[i].y - mu) * rstd * g[col + 1] + bb[col + 1]);
        o[2] = f2b((v[i].z - mu) * rstd * g[col + 2] + bb[col + 2]);
        o[3] = f2b((v[i].w - mu) * rstd * g[col + 3] + bb[col + 3]);
        *reinterpret_cast<u16x4*>(out + (size_t)row * 768 + col) = o;
    }
}

// ------------- weight fp32 [K][N] -> bf16 transposed [N][K] (32x32 tiles) -------------
__global__ __launch_bounds__(256) void wconv_k(const float* __restrict__ W,
                                               u16* __restrict__ WT, int K, int N) {
    __shared__ float tile[32][33];
    const int tx = threadIdx.x, ty = threadIdx.y;
    const int n0 = blockIdx.x * 32, k0 = blockIdx.y * 32;
#pragma unroll
    for (int i = 0; i < 4; ++i)
        tile[ty + i * 8][tx] = W[(size_t)(k0 + ty + i * 8) * N + n0 + tx];
    __syncthreads();
#pragma unroll
    for (int i = 0; i < 4; ++i)
        WT[(size_t)(n0 + ty + i * 8) * K + k0 + tx] = f2b(tile[tx][ty + i * 8]);
}

// ------------- v (from qkv [8192][2304]) -> vT [96*64][1024] bf16 -------------
__global__ __launch_bounds__(256) void vtrans_k(const u16* __restrict__ qkv,
                                                u16* __restrict__ vT) {
    __shared__ u16 tile[32][33];
    const int tx = threadIdx.x, ty = threadIdx.y;
    const int t0 = blockIdx.x * 32, d0 = blockIdx.y * 32, bh = blockIdx.z;
    const int b = bh / 12, hd = bh % 12;
#pragma unroll
    for (int i = 0; i < 4; ++i)
        tile[ty + i * 8][tx] =
            qkv[(size_t)(b * 1024 + t0 + ty + i * 8) * 2304 + 1536 + hd * 64 + d0 + tx];
    __syncthreads();
#pragma unroll
    for (int i = 0; i < 4; ++i)
        vT[(size_t)(bh * 64 + d0 + ty + i * 8) * 1024 + t0 + tx] = tile[tx][ty + i * 8];
}

// ------------- GEMM: C[M,N] = act(A[M,K] @ BT[N,K]^T + bias) (+resid) -------------
// 128x128 tile, BK=32, 4 waves (2x2), each wave 64x64 via 4x4 mfma_16x16x32_bf16.
template <int ACT, int RESID, int OUTBF>
__global__ __launch_bounds__(256) void gemm_bt(const u16* __restrict__ A,
                                               const u16* __restrict__ BT,
                                               const float* __restrict__ bias,
                                               const float* __restrict__ resid,
                                               void* __restrict__ out,
                                               int M, int N, int K) {
    __shared__ u16 As[128 * 32];
    __shared__ u16 Bs[128 * 32];
    const int tid = threadIdx.x, lane = tid & 63;
    const int l15 = lane & 15, lg = lane >> 4;
    const int mBase = blockIdx.y * 128, nBase = blockIdx.x * 128;
    const int w = tid >> 6, wr = w >> 1, wc = w & 1;
    f32x4 acc[4][4] = {};
    const int nsteps = K >> 5;
    for (int kk = 0; kk < nsteps; ++kk) {
        const int k0 = kk << 5;
        __syncthreads();
#pragma unroll
        for (int i = 0; i < 2; ++i) {
            int c = i * 256 + tid;
            int row = c >> 2, colE = (c & 3) << 3;
            async16(As + c * 8, A + (size_t)(mBase + row) * K + k0 + colE);
        }
#pragma unroll
        for (int i = 0; i < 2; ++i) {
            int c = i * 256 + tid;
            int row = c >> 2, colE = (c & 3) << 3;
            async16(Bs + c * 8, BT + (size_t)(nBase + row) * K + k0 + colE);
        }
        __syncthreads();
        bf16x8 af[4], bfr[4];
#pragma unroll
        for (int mi = 0; mi < 4; ++mi)
            af[mi] = load8(As + (wr * 64 + mi * 16 + l15) * 32 + lg * 8);
#pragma unroll
        for (int ni = 0; ni < 4; ++ni)
            bfr[ni] = load8(Bs + (wc * 64 + ni * 16 + l15) * 32 + lg * 8);
#pragma unroll
        for (int mi = 0; mi < 4; ++mi)
#pragma unroll
            for (int ni = 0; ni < 4; ++ni)
                acc[mi][ni] = __builtin_amdgcn_mfma_f32_16x16x32_bf16(
                    af[mi], bfr[ni], acc[mi][ni], 0, 0, 0);
    }
    // epilogue
#pragma unroll
    for (int mi = 0; mi < 4; ++mi) {
#pragma unroll
        for (int ni = 0; ni < 4; ++ni) {
            const int row0 = mBase + wr * 64 + mi * 16 + lg * 4;
            const int col = nBase + wc * 64 + ni * 16 + l15;
            const float bv = bias[col];
#pragma unroll
            for (int r = 0; r < 4; ++r) {
                float v = acc[mi][ni][r] + bv;
                if (ACT == 1) v = gelu_t(v);
                size_t off = (size_t)(row0 + r) * N + col;
                if (RESID) v += resid[off];
                if (OUTBF)
                    ((u16*)out)[off] = f2b(v);
                else
                    ((float*)out)[off] = v;
            }
        }
    }
}

// ------------- causal flash attention -------------
// grid (16 q-tiles, 96 bh); 4 waves, each owns 16 q-rows; KV tiles of 64.
__global__ __launch_bounds__(256) void attn_k(const u16* __restrict__ qkv,
                                              const u16* __restrict__ vT,
                                              u16* __restrict__ y) {
    __shared__ u16 Ks[64 * 64];   // [key][d], chunk-XOR swizzled
    __shared__ u16 Vs[64 * 64];   // [d][key], chunk-XOR swizzled
    __shared__ u16 Ps[4][16 * 64];  // per-wave P [row][key], swizzled
    const int tid = threadIdx.x, lane = tid & 63, w = tid >> 6;
    const int qt = blockIdx.x, bh = blockIdx.y;
    const int b = bh / 12, hd = bh % 12;
    const int l15 = lane & 15, lg = lane >> 4;
    const int qrow0 = qt * 64 + w * 16;

    const u16* qbase =
        qkv + (size_t)(b * 1024 + qrow0 + l15) * 2304 + hd * 64 + lg * 8;
    bf16x8 qf[2];
    qf[0] = load8(qbase);
    qf[1] = load8(qbase + 32);

    f32x4 oacc[4] = {};
    float mrow[4] = {-1e30f, -1e30f, -1e30f, -1e30f};
    float lrow[4] = {0.f, 0.f, 0.f, 0.f};

    for (int j = 0; j <= qt; ++j) {
        __syncthreads();
#pragma unroll
        for (int i = 0; i < 2; ++i) {
            int c = i * 256 + tid;
            int row = c >> 3, sc = ((c & 7) ^ (row & 7)) << 3;
            async16(Ks + c * 8,
                    qkv + (size_t)(b * 1024 + j * 64 + row) * 2304 + 768 + hd * 64 + sc);
        }
#pragma unroll
        for (int i = 0; i < 2; ++i) {
            int c = i * 256 + tid;
            int row = c >> 3, sc = ((c & 7) ^ (row & 7)) << 3;
            async16(Vs + c * 8, vT + (size_t)(bh * 64 + row) * 1024 + j * 64 + sc);
        }
        __syncthreads();

        // S = Q K^T  (D layout: s[ni][r] = S[lg*4+r][ni*16+l15])
        f32x4 s[4] = {};
#pragma unroll
        for (int ks = 0; ks < 2; ++ks) {
#pragma unroll
            for (int ni = 0; ni < 4; ++ni) {
                int key = ni * 16 + l15;
                bf16x8 kf = load8(Ks + key * 64 + (((ks * 4 + lg) ^ (key & 7)) << 3));
                s[ni] = __builtin_amdgcn_mfma_f32_16x16x32_bf16(qf[ks], kf, s[ni], 0, 0, 0);
            }
        }
        // scale + causal mask + row max
        float pmax[4] = {-1e30f, -1e30f, -1e30f, -1e30f};
        const bool diag = (j == qt);
#pragma unroll
        for (int ni = 0; ni < 4; ++ni) {
            int key = j * 64 + ni * 16 + l15;
#pragma unroll
            for (int r = 0; r < 4; ++r) {
                float sv = s[ni][r] * 0.125f;
                if (diag && key > qrow0 + lg * 4 + r) sv = -1e30f;
                s[ni][r] = sv;
                pmax[r] = fmaxf(pmax[r], sv);
            }
        }
#pragma unroll
        for (int off = 1; off < 16; off <<= 1)
#pragma unroll
            for (int r = 0; r < 4; ++r) pmax[r] = fmaxf(pmax[r], __shfl_xor(pmax[r], off));

        float scal[4], psum[4] = {0.f, 0.f, 0.f, 0.f};
#pragma unroll
        for (int r = 0; r < 4; ++r) {
            float mnew = fmaxf(mrow[r], pmax[r]);
            scal[r] = __expf(mrow[r] - mnew);
            mrow[r] = mnew;
        }
        // P = exp(S - m), store bf16 to per-wave LDS (swizzled [row][key])
#pragma unroll
        for (int ni = 0; ni < 4; ++ni) {
            int key = ni * 16 + l15;
#pragma unroll
            for (int r = 0; r < 4; ++r) {
                float pv = __expf(s[ni][r] - mrow[r]);
                psum[r] += pv;
                int row = lg * 4 + r;
                Ps[w][row * 64 + (((key >> 3) ^ (row & 7)) << 3) + (key & 7)] = f2b(pv);
            }
        }
#pragma unroll
        for (int off = 1; off < 16; off <<= 1)
#pragma unroll
            for (int r = 0; r < 4; ++r) psum[r] += __shfl_xor(psum[r], off);
#pragma unroll
        for (int r = 0; r < 4; ++r) lrow[r] = lrow[r] * scal[r] + psum[r];
#pragma unroll
        for (int ni = 0; ni < 4; ++ni)
#pragma unroll
            for (int r = 0; r < 4; ++r) oacc[ni][r] *= scal[r];

        // O += P V
#pragma unroll
        for (int ks = 0; ks < 2; ++ks) {
            bf16x8 pf = load8(&Ps[w][l15 * 64 + (((ks * 4 + lg) ^ (l15 & 7)) << 3)]);
#pragma unroll
            for (int ni = 0; ni < 4; ++ni) {
                int d = ni * 16 + l15;
                bf16x8 vf = load8(Vs + d * 64 + (((ks * 4 + lg) ^ (d & 7)) << 3));
                oacc[ni] = __builtin_amdgcn_mfma_f32_16x16x32_bf16(pf, vf, oacc[ni], 0, 0, 0);
            }
        }
    }
    // normalize + write y bf16 [8192][768]
#pragma unroll
    for (int ni = 0; ni < 4; ++ni) {
        int col = hd * 64 + ni * 16 + l15;
#pragma unroll
        for (int r = 0; r < 4; ++r) {
            int row = qrow0 + lg * 4 + r;
            y[(size_t)(b * 1024 + row) * 768 + col] = f2b(oacc[ni][r] / lrow[r]);
        }
    }
}

extern "C" void kernel_launch(void* const* d_in, const int* in_sizes, int n_in,
                              void* d_out, int out_size, void* d_ws, size_t ws_size,
                              hipStream_t stream) {
    const float* x      = (const float*)d_in[0];
    const float* ln1_g  = (const float*)d_in[1];
    const float* ln1_b  = (const float*)d_in[2];
    const float* w_attn = (const float*)d_in[3];
    const float* b_attn = (const float*)d_in[4];
    const float* w_proj = (const float*)d_in[5];
    const float* b_proj = (const float*)d_in[6];
    const float* ln2_g  = (const float*)d_in[7];
    const float* ln2_b  = (const float*)d_in[8];
    const float* w_fc1  = (const float*)d_in[9];
    const float* b_fc1  = (const float*)d_in[10];
    const float* w_fc2  = (const float*)d_in[11];
    const float* b_fc2  = (const float*)d_in[12];
    float* out = (float*)d_out;

    char* p = (char*)d_ws;
    auto take = [&](size_t n) {
        char* r = p;
        p += (n + 255) & ~(size_t)255;
        return r;
    };
    u16* wT_attn = (u16*)take((size_t)2304 * 768 * 2);
    u16* wT_proj = (u16*)take((size_t)768 * 768 * 2);
    u16* wT_fc1  = (u16*)take((size_t)3072 * 768 * 2);
    u16* wT_fc2  = (u16*)take((size_t)768 * 3072 * 2);
    u16* h       = (u16*)take((size_t)8192 * 768 * 2);   // h1 / h2 (aliased)
    u16* bufA    = (u16*)take((size_t)50331648);         // qkv+vT, later g1
    u16* yb      = (u16*)take((size_t)8192 * 768 * 2);
    float* x1    = (float*)take((size_t)8192 * 768 * 4);
    u16* qkv = bufA;
    u16* vT  = bufA + (size_t)8192 * 2304;  // 37,748,736 B / 2
    u16* g1  = bufA;

    const dim3 tb(32, 8);
    // weight convert+transpose
    wconv_k<<<dim3(2304 / 32, 768 / 32), tb, 0, stream>>>(w_attn, wT_attn, 768, 2304);
    wconv_k<<<dim3(768 / 32, 768 / 32), tb, 0, stream>>>(w_proj, wT_proj, 768, 768);
    wconv_k<<<dim3(3072 / 32, 768 / 32), tb, 0, stream>>>(w_fc1, wT_fc1, 768, 3072);
    wconv_k<<<dim3(768 / 32, 3072 / 32), tb, 0, stream>>>(w_fc2, wT_fc2, 3072, 768);
    // ln1
    ln_k<<<2048, 256, 0, stream>>>(x, ln1_g, ln1_b, h);
    // qkv = h @ w_attn + b_attn  -> bf16
    gemm_bt<0, 0, 1><<<dim3(18, 64), 256, 0, stream>>>(h, wT_attn, b_attn, nullptr,
                                                       qkv, 8192, 2304, 768);
    // v transpose
    vtrans_k<<<dim3(32, 2, 96), tb, 0, stream>>>(qkv, vT);
    // attention
    attn_k<<<dim3(16, 96), 256, 0, stream>>>(qkv, vT, yb);
    // x1 = x + y @ w_proj + b_proj  (fp32)
    gemm_bt<0, 1, 0><<<dim3(6, 64), 256, 0, stream>>>(yb, wT_proj, b_proj, x,
                                                      x1, 8192, 768, 768);
    // ln2
    ln_k<<<2048, 256, 0, stream>>>(x1, ln2_g, ln2_b, h);
    // g1 = gelu(h @ w_fc1 + b_fc1) -> bf16
    gemm_bt<1, 0, 1><<<dim3(24, 64), 256, 0, stream>>>(h, wT_fc1, b_fc1, nullptr,
                                                       g1, 8192, 3072, 768);
    // out = x1 + g1 @ w_fc2 + b_fc2  (fp32)
    gemm_bt<0, 1, 0><<<dim3(6, 64), 256, 0, stream>>>(g1, wT_fc2, b_fc2, x1,
                                                      out, 8192, 768, 3072);
}